// Round 1
// baseline (915.226 us; speedup 1.0000x reference)
//
#include <hip/hip_runtime.h>
#include <stdint.h>

#define F_IN  128
#define HID   16
#define F_OUT 128

// ---------- degree / normalization ----------

__global__ void k_init_deg(float* __restrict__ deg, int n) {
    int i = blockIdx.x * blockDim.x + threadIdx.x;
    if (i < n) deg[i] = 1.0f;   // self-loop contributes 1
}

__global__ void k_count_deg(const int* __restrict__ dst, float* __restrict__ deg, int E) {
    int e = blockIdx.x * blockDim.x + threadIdx.x;
    if (e < E) atomicAdd(&deg[dst[e]], 1.0f);
}

__global__ void k_dinv(float* __restrict__ deg, int n) {
    int i = blockIdx.x * blockDim.x + threadIdx.x;
    if (i < n) deg[i] = rsqrtf(deg[i]);   // deg >= 1 always
}

// ---------- layer 1 transform: g1 = dinv * (x @ W1); acc init = g1 ----------
// block = 256 threads = 16 nodes x 16 features
__global__ void k_transform1(const float* __restrict__ x, const float* __restrict__ W1,
                             const float* __restrict__ dinv,
                             float* __restrict__ g1, float* __restrict__ acc, int n) {
    __shared__ float sW[F_IN * HID];   // 8 KB, layout [k][f]
    __shared__ float sX[16 * F_IN];    // 8 KB
    int t = threadIdx.x;
    for (int i = t; i < F_IN * HID; i += 256) sW[i] = W1[i];
    int node0 = blockIdx.x * 16;
    const float* xb = x + (size_t)node0 * F_IN;
    for (int i = t; i < 16 * F_IN; i += 256) {
        int node = node0 + (i >> 7);
        sX[i] = (node < n) ? xb[i] : 0.0f;
    }
    __syncthreads();
    int nl = t >> 4;        // local node 0..15
    int f  = t & 15;        // feature 0..15
    int node = node0 + nl;
    if (node >= n) return;
    float s = 0.0f;
#pragma unroll
    for (int k = 0; k < F_IN; ++k)
        s += sX[nl * F_IN + k] * sW[k * HID + f];
    float g = dinv[node] * s;
    size_t o = (size_t)node * HID + f;
    g1[o]  = g;
    acc[o] = g;   // self-loop term pre-seeded
}

// ---------- scatter: acc[dst] += g[src], 4 threads per edge ----------
__global__ void k_scatter(const int* __restrict__ ei, const float* __restrict__ g,
                          float* __restrict__ acc, int E) {
    int t = blockIdx.x * blockDim.x + threadIdx.x;
    int e = t >> 2;
    int p = t & 3;
    if (e >= E) return;
    int s = ei[e];
    int d = ei[E + e];
    const float4 v = *(const float4*)(g + (size_t)s * HID + p * 4);
    float* a = acc + (size_t)d * HID + p * 4;
    atomicAdd(a + 0, v.x);
    atomicAdd(a + 1, v.y);
    atomicAdd(a + 2, v.z);
    atomicAdd(a + 3, v.w);
}

// ---------- finalize layer 1: a1 = relu(dinv*acc + b1); g2 = dinv*a1 ----------
// writes g2 into both g (for gather) and acc (self-loop seed for pass 2)
__global__ void k_finalize1(const float* __restrict__ b1, const float* __restrict__ dinv,
                            float* __restrict__ g, float* __restrict__ acc, int n) {
    int t = blockIdx.x * blockDim.x + threadIdx.x;
    if (t >= n * HID) return;
    int i = t >> 4;
    int f = t & 15;
    float di = dinv[i];
    float a = fmaxf(di * acc[t] + b1[f], 0.0f);
    float gg = di * a;
    g[t]   = gg;
    acc[t] = gg;
}

// ---------- layer 2 transform: out = relu((dinv*acc) @ W2 + b2) ----------
// block = 256 threads = 2 nodes x 128 outputs
__global__ void k_transform2(const float* __restrict__ acc, const float* __restrict__ W2,
                             const float* __restrict__ b2, const float* __restrict__ dinv,
                             float* __restrict__ out, int n) {
    __shared__ float sW[HID * F_OUT];  // 8 KB, layout [f][d]
    __shared__ float sB[F_OUT];
    __shared__ float sV[2 * HID];
    int t = threadIdx.x;
    for (int i = t; i < HID * F_OUT; i += 256) sW[i] = W2[i];
    if (t < F_OUT) sB[t] = b2[t];
    int node0 = blockIdx.x * 2;
    if (t < 2 * HID) {
        int node = node0 + (t >> 4);
        sV[t] = (node < n) ? dinv[node] * acc[(size_t)node * HID + (t & 15)] : 0.0f;
    }
    __syncthreads();
    int nl = t >> 7;       // 0..1
    int d  = t & 127;
    int node = node0 + nl;
    if (node >= n) return;
    float s = 0.0f;
#pragma unroll
    for (int f = 0; f < HID; ++f)
        s += sV[nl * HID + f] * sW[f * F_OUT + d];
    out[(size_t)node * F_OUT + d] = fmaxf(s + sB[d], 0.0f);
}

extern "C" void kernel_launch(void* const* d_in, const int* in_sizes, int n_in,
                              void* d_out, int out_size, void* d_ws, size_t ws_size,
                              hipStream_t stream) {
    const float* x  = (const float*)d_in[0];
    const int*   ei = (const int*)d_in[1];     // [2, E] row-major, int32 per harness
    const float* W1 = (const float*)d_in[2];
    const float* b1 = (const float*)d_in[3];
    const float* W2 = (const float*)d_in[4];
    const float* b2 = (const float*)d_in[5];
    float* out = (float*)d_out;

    const int N = in_sizes[0] / F_IN;
    const int E = in_sizes[1] / 2;

    float* dinv = (float*)d_ws;                    // N floats
    float* bufA = dinv + N;                        // N*HID floats (gather source)
    float* bufB = bufA + (size_t)N * HID;          // N*HID floats (accumulator)

    k_init_deg <<<(N + 255) / 256, 256, 0, stream>>>(dinv, N);
    k_count_deg<<<(E + 255) / 256, 256, 0, stream>>>(ei + E, dinv, E);
    k_dinv     <<<(N + 255) / 256, 256, 0, stream>>>(dinv, N);

    k_transform1<<<(N + 15) / 16, 256, 0, stream>>>(x, W1, dinv, bufA, bufB, N);
    k_scatter   <<<((size_t)E * 4 + 255) / 256, 256, 0, stream>>>(ei, bufA, bufB, E);
    k_finalize1 <<<((size_t)N * HID + 255) / 256, 256, 0, stream>>>(b1, dinv, bufA, bufB, N);
    k_scatter   <<<((size_t)E * 4 + 255) / 256, 256, 0, stream>>>(ei, bufA, bufB, E);
    k_transform2<<<(N + 1) / 2, 256, 0, stream>>>(bufB, W2, b2, dinv, out, N);
}

// Round 2
// 419.308 us; speedup vs baseline: 2.1827x; 2.1827x over previous
//
#include <hip/hip_runtime.h>
#include <stdint.h>

#define F_IN  128
#define HID   16
#define F_OUT 128
#define SCAN_CHUNK 1024   // elements per scan block (256 threads x 4)

// ---------- CSR build ----------

__global__ void k_zero(int* __restrict__ p, int n) {
    int i = blockIdx.x * blockDim.x + threadIdx.x;
    if (i < n) p[i] = 0;
}

__global__ void k_hist(const int* __restrict__ dst, int* __restrict__ cnt, int E) {
    int e = blockIdx.x * blockDim.x + threadIdx.x;
    if (e < E) atomicAdd(&cnt[dst[e]], 1);
}

// per-block sums of cnt (1024 elements / block)
__global__ void k_scan_a(const int* __restrict__ cnt, int* __restrict__ bsum, int n) {
    __shared__ int sd[256];
    int base = blockIdx.x * SCAN_CHUNK;
    int t = threadIdx.x;
    int s = 0;
#pragma unroll
    for (int k = 0; k < 4; ++k) {
        int i = base + t * 4 + k;
        if (i < n) s += cnt[i];
    }
    sd[t] = s; __syncthreads();
    for (int o = 128; o > 0; o >>= 1) {
        if (t < o) sd[t] += sd[t + o];
        __syncthreads();
    }
    if (t == 0) bsum[blockIdx.x] = sd[0];
}

// exclusive scan of block sums (single block, nb <= 256)
__global__ void k_scan_b(int* __restrict__ bsum, int nb) {
    __shared__ int sd[256];
    int t = threadIdx.x;
    int v = (t < nb) ? bsum[t] : 0;
    sd[t] = v; __syncthreads();
    for (int o = 1; o < 256; o <<= 1) {
        int x = (t >= o) ? sd[t - o] : 0;
        __syncthreads();
        sd[t] += x;
        __syncthreads();
    }
    if (t < nb) bsum[t] = sd[t] - v;   // exclusive
}

// final: row_start, cursor(copy), dinv = rsqrt(deg+1)
__global__ void k_scan_c(const int* __restrict__ cnt, const int* __restrict__ bsum,
                         int* __restrict__ row_start, int* __restrict__ cursor,
                         float* __restrict__ dinv, int n) {
    __shared__ int ts[256];
    int base = blockIdx.x * SCAN_CHUNK;
    int t = threadIdx.x;
    int c[4]; int s = 0;
#pragma unroll
    for (int k = 0; k < 4; ++k) {
        int i = base + t * 4 + k;
        c[k] = (i < n) ? cnt[i] : 0;
        s += c[k];
    }
    ts[t] = s; __syncthreads();
    int v = s;
    for (int o = 1; o < 256; o <<= 1) {
        int x = (t >= o) ? ts[t - o] : 0;
        __syncthreads();
        ts[t] += x;
        __syncthreads();
    }
    int off = bsum[blockIdx.x] + ts[t] - v;
#pragma unroll
    for (int k = 0; k < 4; ++k) {
        int i = base + t * 4 + k;
        if (i < n) {
            row_start[i] = off;
            cursor[i]    = off;
            dinv[i]      = rsqrtf((float)(c[k] + 1));
            off += c[k];
        }
    }
}

__global__ void k_fill(const int* __restrict__ ei, int* __restrict__ cursor,
                       int* __restrict__ srcs, int E) {
    int e = blockIdx.x * blockDim.x + threadIdx.x;
    if (e >= E) return;
    int s = ei[e];
    int d = ei[E + e];
    int pos = atomicAdd(&cursor[d], 1);
    srcs[pos] = s;
}

// ---------- layer 1 transform: g1 = dinv * (x @ W1) ----------
__global__ void k_transform1(const float* __restrict__ x, const float* __restrict__ W1,
                             const float* __restrict__ dinv,
                             float* __restrict__ g1, int n) {
    __shared__ float sW[F_IN * HID];   // [k][f]
    __shared__ float sX[16 * F_IN];
    int t = threadIdx.x;
    for (int i = t; i < F_IN * HID; i += 256) sW[i] = W1[i];
    int node0 = blockIdx.x * 16;
    const float* xb = x + (size_t)node0 * F_IN;
    for (int i = t; i < 16 * F_IN; i += 256) {
        int node = node0 + (i >> 7);
        sX[i] = (node < n) ? xb[i] : 0.0f;
    }
    __syncthreads();
    int nl = t >> 4, f = t & 15;
    int node = node0 + nl;
    if (node >= n) return;
    float s = 0.0f;
#pragma unroll
    for (int k = 0; k < F_IN; ++k)
        s += sX[nl * F_IN + k] * sW[k * HID + f];
    g1[(size_t)node * HID + f] = dinv[node] * s;
}

// ---------- gather-aggregate: out[i] = g[i] + sum_j g[srcs[rs+j]] ----------
// 4 threads/node, float4 per thread. EP1: fused relu/bias/scale epilogue.
template<bool EP1>
__global__ void k_gather(const float* __restrict__ g, const int* __restrict__ srcs,
                         const int* __restrict__ row_start, const int* __restrict__ cnt,
                         const float* __restrict__ dinv, const float* __restrict__ b1,
                         float* __restrict__ outb, int n) {
    int t = blockIdx.x * blockDim.x + threadIdx.x;
    int node = t >> 2;
    int p = t & 3;
    if (node >= n) return;
    int rs  = row_start[node];
    int deg = cnt[node];
    float4 acc = *(const float4*)(g + (size_t)node * HID + p * 4);
    int j = 0;
    for (; j + 2 <= deg; j += 2) {
        int s0 = srcs[rs + j];
        int s1 = srcs[rs + j + 1];
        float4 v0 = *(const float4*)(g + (size_t)s0 * HID + p * 4);
        float4 v1 = *(const float4*)(g + (size_t)s1 * HID + p * 4);
        acc.x += v0.x + v1.x; acc.y += v0.y + v1.y;
        acc.z += v0.z + v1.z; acc.w += v0.w + v1.w;
    }
    if (j < deg) {
        int s0 = srcs[rs + j];
        float4 v0 = *(const float4*)(g + (size_t)s0 * HID + p * 4);
        acc.x += v0.x; acc.y += v0.y; acc.z += v0.z; acc.w += v0.w;
    }
    if (EP1) {
        float di = dinv[node];
        acc.x = di * fmaxf(di * acc.x + b1[p * 4 + 0], 0.0f);
        acc.y = di * fmaxf(di * acc.y + b1[p * 4 + 1], 0.0f);
        acc.z = di * fmaxf(di * acc.z + b1[p * 4 + 2], 0.0f);
        acc.w = di * fmaxf(di * acc.w + b1[p * 4 + 3], 0.0f);
    }
    *(float4*)(outb + (size_t)node * HID + p * 4) = acc;
}

// ---------- layer 2 transform: out = relu((dinv*agg) @ W2 + b2) ----------
__global__ void k_transform2(const float* __restrict__ agg, const float* __restrict__ W2,
                             const float* __restrict__ b2, const float* __restrict__ dinv,
                             float* __restrict__ out, int n) {
    __shared__ float sW[HID * F_OUT];  // [f][d]
    __shared__ float sB[F_OUT];
    __shared__ float sV[2 * HID];
    int t = threadIdx.x;
    for (int i = t; i < HID * F_OUT; i += 256) sW[i] = W2[i];
    if (t < F_OUT) sB[t] = b2[t];
    int node0 = blockIdx.x * 2;
    if (t < 2 * HID) {
        int node = node0 + (t >> 4);
        sV[t] = (node < n) ? dinv[node] * agg[(size_t)node * HID + (t & 15)] : 0.0f;
    }
    __syncthreads();
    int nl = t >> 7, d = t & 127;
    int node = node0 + nl;
    if (node >= n) return;
    float s = 0.0f;
#pragma unroll
    for (int f = 0; f < HID; ++f)
        s += sV[nl * HID + f] * sW[f * F_OUT + d];
    out[(size_t)node * F_OUT + d] = fmaxf(s + sB[d], 0.0f);
}

extern "C" void kernel_launch(void* const* d_in, const int* in_sizes, int n_in,
                              void* d_out, int out_size, void* d_ws, size_t ws_size,
                              hipStream_t stream) {
    const float* x  = (const float*)d_in[0];
    const int*   ei = (const int*)d_in[1];
    const float* W1 = (const float*)d_in[2];
    const float* b1 = (const float*)d_in[3];
    const float* W2 = (const float*)d_in[4];
    const float* b2 = (const float*)d_in[5];
    float* out = (float*)d_out;

    const int N = in_sizes[0] / F_IN;
    const int E = in_sizes[1] / 2;

    // workspace layout
    float* dinv      = (float*)d_ws;               // N
    int*   cnt       = (int*)(dinv + N);           // N
    int*   row_start = cnt + N;                    // N
    int*   cursor    = row_start + N;              // N
    int*   bsum      = cursor + N;                 // 256
    int*   srcs      = bsum + 256;                 // E
    float* bufA      = (float*)(srcs + E);         // N*HID
    float* bufB      = bufA + (size_t)N * HID;     // N*HID

    const int nb = (N + SCAN_CHUNK - 1) / SCAN_CHUNK;   // 98 for N=100000

    k_zero  <<<(N + 255) / 256, 256, 0, stream>>>(cnt, N);
    k_hist  <<<(E + 255) / 256, 256, 0, stream>>>(ei + E, cnt, E);
    k_scan_a<<<nb, 256, 0, stream>>>(cnt, bsum, N);
    k_scan_b<<<1, 256, 0, stream>>>(bsum, nb);
    k_scan_c<<<nb, 256, 0, stream>>>(cnt, bsum, row_start, cursor, dinv, N);
    k_fill  <<<(E + 255) / 256, 256, 0, stream>>>(ei, cursor, srcs, E);

    k_transform1<<<(N + 15) / 16, 256, 0, stream>>>(x, W1, dinv, bufA, N);
    k_gather<true> <<<((size_t)N * 4 + 255) / 256, 256, 0, stream>>>(
        bufA, srcs, row_start, cnt, dinv, b1, bufB, N);
    k_gather<false><<<((size_t)N * 4 + 255) / 256, 256, 0, stream>>>(
        bufB, srcs, row_start, cnt, dinv, b1, bufA, N);
    k_transform2<<<(N + 1) / 2, 256, 0, stream>>>(bufA, W2, b2, dinv, out, N);
}